// Round 9
// baseline (2265.982 us; speedup 1.0000x reference)
//
#include <hip/hip_runtime.h>
#include <cstdint>
#include <cstddef>

#define IN_F 512
#define OUT_F 1024
#define BATCH 8192
#define W_K 1535   // IN_F + OUT_F - 1
#define SROW 132   // padded t-dimension (16B-aligned rows, conflict-free quads)

// ---------------------------------------------------------------------------
__global__ __launch_bounds__(256) void k_fill(float* __restrict__ out, float val) {
  const size_t i = ((size_t)blockIdx.x * 256 + threadIdx.x) * 4;
  float4 v; v.x = v.y = v.z = v.w = val;
  *(float4*)(out + i) = v;
}

// ---------------------------------------------------------------------------
// K1: xw = x @ Wx.T + bias mimicking numpy/OpenBLAS sgemm fp32 rounding:
// per C element ONE fp32 accumulator, FMA, k STRICTLY ascending (BLAS rank-1
// microkernel order; kc-blocking round-trips through fp32 exactly), then a
// single RNE add of bias. Intended to be bit-identical to np's xw.
// ---------------------------------------------------------------------------
__global__ __launch_bounds__(256) void k_gemm32(const float* __restrict__ x,
                                                const float* __restrict__ w,
                                                const float* __restrict__ bias,
                                                float* __restrict__ xw) {
  __shared__ float xs[64][33];
  __shared__ float wsh[64][33];
  const int t = threadIdx.x;
  const int bsub = t >> 4;    // 0..15 -> 4 b-rows
  const int esub = t & 15;    // 0..15 -> 4 e-cols
  const int bm = blockIdx.x;  // 128 tiles of 64 rows
  const int bn = blockIdx.y;  // 16 tiles of 64 cols
  const int srow = t >> 2;          // staging row 0..63
  const int scol = (t & 3) * 8;     // staging k-offset
  const float* xbase = x + (size_t)(bm * 64 + srow) * IN_F + scol;
  const float* wbase = w + (size_t)(bn * 64 + srow) * W_K + scol;

  float acc[4][4];
#pragma unroll
  for (int a = 0; a < 4; ++a)
#pragma unroll
    for (int b = 0; b < 4; ++b) acc[a][b] = 0.0f;

  for (int k0 = 0; k0 < IN_F; k0 += 32) {
    float xv[8], wv[8];
#pragma unroll
    for (int c = 0; c < 8; ++c) { xv[c] = xbase[k0 + c]; wv[c] = wbase[k0 + c]; }
    __syncthreads();
#pragma unroll
    for (int c = 0; c < 8; ++c) { xs[srow][scol + c] = xv[c]; wsh[srow][scol + c] = wv[c]; }
    __syncthreads();
#pragma unroll
    for (int k = 0; k < 32; ++k) {   // ascending k: exact BLAS accumulation order
      const float a0 = xs[bsub * 4 + 0][k], a1 = xs[bsub * 4 + 1][k];
      const float a2 = xs[bsub * 4 + 2][k], a3 = xs[bsub * 4 + 3][k];
      const float b0 = wsh[esub * 4 + 0][k], b1 = wsh[esub * 4 + 1][k];
      const float b2 = wsh[esub * 4 + 2][k], b3 = wsh[esub * 4 + 3][k];
      acc[0][0] = fmaf(a0, b0, acc[0][0]); acc[0][1] = fmaf(a0, b1, acc[0][1]);
      acc[0][2] = fmaf(a0, b2, acc[0][2]); acc[0][3] = fmaf(a0, b3, acc[0][3]);
      acc[1][0] = fmaf(a1, b0, acc[1][0]); acc[1][1] = fmaf(a1, b1, acc[1][1]);
      acc[1][2] = fmaf(a1, b2, acc[1][2]); acc[1][3] = fmaf(a1, b3, acc[1][3]);
      acc[2][0] = fmaf(a2, b0, acc[2][0]); acc[2][1] = fmaf(a2, b1, acc[2][1]);
      acc[2][2] = fmaf(a2, b2, acc[2][2]); acc[2][3] = fmaf(a2, b3, acc[2][3]);
      acc[3][0] = fmaf(a3, b0, acc[3][0]); acc[3][1] = fmaf(a3, b1, acc[3][1]);
      acc[3][2] = fmaf(a3, b2, acc[3][2]); acc[3][3] = fmaf(a3, b3, acc[3][3]);
    }
  }

#pragma unroll
  for (int ie = 0; ie < 4; ++ie) {
    const int e = bn * 64 + esub * 4 + ie;
    const float bv = bias[e];
#pragma unroll
    for (int ib = 0; ib < 4; ++ib) {
      const int b = bm * 64 + bsub * 4 + ib;
      xw[(size_t)b * OUT_F + e] = acc[ib][ie] + bv;   // single RNE add, like np
    }
  }
}

// ---------------------------------------------------------------------------
// K2: the scan, mimicking np's per-step `xw_i + out[:, :1023] @ wo_row` with
// OpenBLAS sgemv_t fp32 rounding:
//   - 8 partial sums P_m = sum over j ≡ m (mod 8), j ascending, FMA
//     (vector region j < 1016 only),
//   - AVX horizontal tree  ((P0+P4)+(P2+P6)) + ((P1+P5)+(P3+P7)),
//   - scalar tail j = 1016..1022 appended sequentially,
//   - logit = xw_i + dot   (one RNE add),
//   - sample = u < (float)(1/(1+exp(-(double)logit)))  [σ near-correctly-rounded].
// Zero terms (s_j=0 or j>=i) contribute exactly +0.0 in fp32 — skipping them
// is bit-neutral, so partials only need written entries; unwritten LDS is
// zero-initialized.
// Wave layout: 8 rows/wave (g = lane>>3), lane m = lane&7 owns partial m.
// smp[g][m][t] holds sample s_{m+8t} as float (permuted write at step end);
// tail samples j>=1016 live in tail_smp so the vector region stays clean.
// 1024 blocks x 64 threads (1 wave — no __syncthreads needed).
// ---------------------------------------------------------------------------
__global__ __launch_bounds__(64) void k_scan32(const float* __restrict__ w,
                                               const float* __restrict__ u,
                                               const float* __restrict__ xw,
                                               float* __restrict__ out_s,
                                               float* __restrict__ out_l) {
  __shared__ float smp[8][8][SROW];   // 33.8 KiB
  __shared__ float wop[8][SROW];      // 4.2 KiB
  __shared__ float tail_smp[8][8];    // samples j in [1016,1024)
  const int lane = threadIdx.x;
  const int g = lane >> 3;   // row group 0..7
  const int m = lane & 7;    // partial index

  // zero-init LDS (harness poisons; zeros are semantically exact filler)
  for (int idx = lane; idx < 8 * 8 * SROW; idx += 64) (&smp[0][0][0])[idx] = 0.0f;
  for (int idx = lane; idx < 8 * SROW; idx += 64) (&wop[0][0])[idx] = 0.0f;
  if (lane < 8) { for (int jj = 0; jj < 8; ++jj) tail_smp[lane][jj] = 0.0f; }

  const int r = blockIdx.x * 8 + g;
  const float* xwr = xw + (size_t)r * OUT_F;
  const float* ur = u + (size_t)r * OUT_F;
  float* osr = out_s + (size_t)r * OUT_F;
  float* olr = out_l + (size_t)r * OUT_F;

  for (int i = 0; i < OUT_F; ++i) {
    // stage Wo row i (w[i][512+j], j<1023) into permuted layout wop[j%8][j/8]
    const float* worow = w + (size_t)i * W_K + IN_F;
    for (int jj = lane; jj < OUT_F - 1; jj += 64)
      wop[jj & 7][jj >> 3] = worow[jj];

    // vector-region partial P_m: j = m + 8t, ascending t, FMA (product exact)
    float P = 0.0f;
    const int ilim = (i < 1016) ? i : 1016;
    const int tcap = (ilim + 7) >> 3;        // overshoot entries are exact zeros
    const int qn = (tcap + 3) >> 2;
    const float* sp = &smp[g][m][0];
    const float* wp = &wop[m][0];
    for (int q = 0; q < qn; ++q) {
      const float4 s4 = *(const float4*)(sp + 4 * q);
      const float4 w4 = *(const float4*)(wp + 4 * q);
      P = fmaf(s4.x, w4.x, P);
      P = fmaf(s4.y, w4.y, P);
      P = fmaf(s4.z, w4.z, P);
      P = fmaf(s4.w, w4.w, P);
    }

    // AVX horizontal tree: ((P0+P4)+(P2+P6)) + ((P1+P5)+(P3+P7)) on lane m==0
    float t1 = P + __shfl_xor(P, 4);
    float t2 = t1 + __shfl_xor(t1, 2);
    float T = t2 + __shfl_xor(t2, 1);

    if (m == 0) {
      // scalar tail j = 1016..1022, ascending (zeros exact when j>=i)
#pragma unroll
      for (int jj = 0; jj < 7; ++jj)
        T = fmaf(tail_smp[g][jj], wop[jj][127], T);
      const float L = xwr[i] + T;                      // np: xw_i + dot
      const double sd = 1.0 / (1.0 + exp(-(double)L)); // σ, near-correctly-rounded
      const float sig = (float)sd;
      const float s = (ur[i] < sig) ? 1.0f : 0.0f;
      if (i < 1016) smp[g][i & 7][i >> 3] = s;
      else tail_smp[g][i - 1016] = s;
      osr[i] = s;
      olr[i] = L;
    }
  }
}

// ---------------------------------------------------------------------------
extern "C" void kernel_launch(void* const* d_in, const int* in_sizes, int n_in,
                              void* d_out, int out_size, void* d_ws, size_t ws_size,
                              hipStream_t stream) {
  float* out_s = (float*)d_out;                      // samples (B x OUT_F) fp32
  float* out_l = out_s + (size_t)BATCH * OUT_F;      // logits  (B x OUT_F) fp32
  const int nfill = (BATCH * OUT_F) / (256 * 4);

  const bool shapes_ok =
      n_in == 4 &&
      in_sizes[0] == BATCH * IN_F && in_sizes[1] == OUT_F * W_K &&
      in_sizes[2] == OUT_F && in_sizes[3] == BATCH * OUT_F &&
      out_size == 2 * BATCH * OUT_F;
  if (!shapes_ok) {
    k_fill<<<nfill, 256, 0, stream>>>(out_s, 11.0f);
    return;
  }

  const size_t xw_bytes = (size_t)BATCH * OUT_F * sizeof(float);  // 32 MiB
  if (ws_size < xw_bytes) {
    k_fill<<<nfill, 256, 0, stream>>>(out_s, 7.0f);
    return;
  }

  const float* x = (const float*)d_in[0];     // fp32 (8192 x 512)
  const float* w = (const float*)d_in[1];     // fp32 (1024 x 1535)
  const float* bias = (const float*)d_in[2];  // fp32 (1024)
  const float* u = (const float*)d_in[3];     // fp32 (8192 x 1024)
  float* xw = (float*)d_ws;                   // 32 MiB

  k_gemm32<<<dim3(BATCH / 64, OUT_F / 64), 256, 0, stream>>>(x, w, bias, xw);
  k_scan32<<<BATCH / 8, 64, 0, stream>>>(w, u, xw, out_s, out_l);
}